// Round 5
// baseline (90.851 us; speedup 1.0000x reference)
//
#include <hip/hip_runtime.h>
#include <stdint.h>

// ONNX NMS: B=8, C=16, N=2048, MAX_OUT=100.
// Kernel A (256 blocks x 512 thr): sort each (b,c)'s two 1024-halves
//   descending into d_ws (register bitonic for strides<=64 via shfl_xor,
//   LDS only for strides>=128).
// Kernel B (128 blocks x 512 thr): merge-path merge of the two descending
//   runs (each thread binary-searches its diagonal, emits 4 merged elements,
//   gathers the boxes for its own positions — zero merge barriers), then
//   chunked greedy: 128x128 intra-chunk suppression bitmatrix + prior-kept
//   pass, single-wave ballot cascade (no LDS in the serial walk), emit.
// Keys: (flipped score bits)<<32 | (0xFFFFFFFF - idx) -> unique; descending
// sort == stable argsort(-scores). IoU in the reference's exact fp32 op order.

#define NBOX 2048
#define HALF 1024
#define TA 512
#define TB 512
#define CHUNK 128
#define MAXKEEP 256

typedef unsigned long long u64;

__device__ __forceinline__ unsigned flipf(float s) {
  unsigned b = __float_as_uint(s);
  return (b & 0x80000000u) ? ~b : (b | 0x80000000u);
}

__device__ __forceinline__ u64 ce_x(u64 v, int s, bool up, int lane) {
  u64 p = __shfl_xor(v, s, 64);
  bool lower = ((lane & s) == 0);
  u64 mx = v > p ? v : p;
  u64 mn = v > p ? p : v;
  return (up == lower) ? mx : mn;
}

// ---------------- Kernel A: sort one 1024-half of one (b,c), descending ----
__global__ __launch_bounds__(TA) void sort_half_kernel(
    const float* __restrict__ scores, u64* __restrict__ wsKeys, int C)
{
  __shared__ u64 sk[HALF];                 // 8 KB
  const int tid = threadIdx.x, lane = tid & 63, w = tid >> 6;   // 8 waves
  const int bc = blockIdx.x >> 1;
  const int h  = blockIdx.x & 1;
  const float* cls = scores + (size_t)bc * NBOX + h * HALF;

  const int p0 = w * 128 + lane;
  const int p1 = p0 + 64;
  const int g0 = h * HALF + p0, g1 = h * HALF + p1;
  u64 e0 = ((u64)flipf(cls[p0]) << 32) | (0xFFFFFFFFu - (unsigned)g0);
  u64 e1 = ((u64)flipf(cls[p1]) << 32) | (0xFFFFFFFFu - (unsigned)g1);

  #pragma unroll
  for (int k = 2; k <= 64; k <<= 1) {
    #pragma unroll
    for (int s = k >> 1; s >= 1; s >>= 1) {
      bool up0 = ((lane & k) == 0);
      bool up1 = (((64 + lane) & k) == 0);
      e0 = ce_x(e0, s, up0, lane);
      e1 = ce_x(e1, s, up1, lane);
    }
  }
  { // k = 128
    bool up = ((w & 1) == 0);
    u64 mx = e0 > e1 ? e0 : e1, mn = e0 > e1 ? e1 : e0;
    e0 = up ? mx : mn; e1 = up ? mn : mx;
    #pragma unroll
    for (int s = 32; s >= 1; s >>= 1) {
      e0 = ce_x(e0, s, up, lane);
      e1 = ce_x(e1, s, up, lane);
    }
  }
  sk[p0] = e0; sk[p1] = e1;
  __syncthreads();

  for (int k = 256; k <= HALF; k <<= 1) {
    for (int s = k >> 1; s >= 128; s >>= 1) {
      unsigned i = ((tid & ~(s - 1)) << 1) | (tid & (s - 1));
      unsigned j = i | (unsigned)s;
      u64 a = sk[i], bb = sk[j];
      bool up = ((i & (unsigned)k) == 0);
      bool sw = up ? (a < bb) : (a > bb);
      if (sw) { sk[i] = bb; sk[j] = a; }
      __syncthreads();
    }
    e0 = sk[p0]; e1 = sk[p1];
    bool up = (((unsigned)p0 & (unsigned)k) == 0);
    u64 mx = e0 > e1 ? e0 : e1, mn = e0 > e1 ? e1 : e0;
    e0 = up ? mx : mn; e1 = up ? mn : mx;
    #pragma unroll
    for (int s = 32; s >= 1; s >>= 1) {
      e0 = ce_x(e0, s, up, lane);
      e1 = ce_x(e1, s, up, lane);
    }
    if (k < HALF) { sk[p0] = e0; sk[p1] = e1; __syncthreads(); }
  }

  u64* dst = wsKeys + (size_t)bc * NBOX + h * HALF;
  dst[p0] = e0; dst[p1] = e1;              // both halves descending
}

// ---------------- Kernel B: merge-path + greedy NMS + emit ----------------
__global__ __launch_bounds__(TB) void nms_kernel(
    const float* __restrict__ boxes,
    const u64* __restrict__ wsKeys,
    const int* __restrict__ maxOutPtr,
    const float* __restrict__ iouThrPtr,
    const float* __restrict__ scoreThrPtr,
    int* __restrict__ out, int B, int C, int slots)
{
  __shared__ u64 rk[NBOX];                                                // 16 KB
  __shared__ int sidx[NBOX];                                              // 8 KB
  __shared__ float sx1[NBOX], sy1[NBOX], sx2[NBOX], sy2[NBOX], sar[NBOX]; // 40 KB
  __shared__ unsigned colmask[CHUNK][4];   // bit i of colmask[j]: i suppresses j
  __shared__ unsigned char suppPre[CHUNK];
  __shared__ int keptPos[MAXKEEP];
  __shared__ int Vsh, cntSh;

  const int tid = threadIdx.x, lane = tid & 63, w = tid >> 6;   // 8 waves
  const int bc = blockIdx.x;
  const int b = bc / C, c = bc % C;
  const float iouT = iouThrPtr[0];
  const unsigned thrU = flipf(scoreThrPtr[0]);
  int mOut = maxOutPtr[0];
  if (mOut > slots) mOut = slots;
  if (mOut > MAXKEEP) mOut = MAXKEEP;
  if (mOut < 0) mOut = 0;

  if (tid == 0) { Vsh = 0; cntSh = 0; }

  // load both descending runs; count valid via ballots
  const u64* src = wsKeys + (size_t)bc * NBOX;
  int pop = 0;
  #pragma unroll
  for (int p = 0; p < NBOX; p += TB) {
    u64 v = src[p + tid];
    rk[p + tid] = v;
    pop += __popcll(__ballot((unsigned)(v >> 32) > thrU));
  }
  if (tid < CHUNK * 4) ((unsigned*)colmask)[tid] = 0;   // first-chunk clear
  if (tid < CHUNK) suppPre[tid] = 0;
  __syncthreads();
  if (lane == 0) atomicAdd(&Vsh, pop);
  __syncthreads();
  const int V = Vsh;

  // merge-path: thread t emits merged[4t..4t+4); gathers its own boxes
  {
    const u64* r0 = rk;
    const u64* r1 = rk + HALF;
    int d = tid * 4;
    int lo = d - HALF; if (lo < 0) lo = 0;
    int hi = d < HALF ? d : HALF;
    while (lo < hi) {                       // find a = count from r0 in top-d
      int a = (lo + hi) >> 1;
      if (r0[a] > r1[d - a - 1]) lo = a + 1; else hi = a;
    }
    int a = lo, bb = d - lo;
    const float4* bx = (const float4*)boxes + (size_t)b * NBOX;
    #pragma unroll
    for (int q = 0; q < 4; ++q) {
      u64 v0 = (a < HALF) ? r0[a] : 0;
      u64 v1 = (bb < HALF) ? r1[bb] : 0;
      bool take0 = (bb >= HALF) || ((a < HALF) && (v0 > v1));
      u64 v = take0 ? v0 : v1;
      if (take0) a++; else bb++;
      int p = d + q;
      int idx = (int)(0xFFFFFFFFu - (unsigned)v);
      sidx[p] = idx;
      if (p < V) {
        float4 f = bx[idx];
        sx1[p] = f.x; sy1[p] = f.y; sx2[p] = f.z; sy2[p] = f.w;
        sar[p] = (f.z - f.x) * (f.w - f.y);
      }
    }
  }
  __syncthreads();

  // chunked greedy
  int cnt = 0;
  for (int c0 = 0; c0 < V && cnt < mOut; c0 += CHUNK) {
    int clen = V - c0; if (clen > CHUNK) clen = CHUNK;

    if (c0 > 0) {                           // re-clear for later chunks
      if (tid < CHUNK * 4) ((unsigned*)colmask)[tid] = 0;
      if (tid < CHUNK) suppPre[tid] = 0;
      __syncthreads();
    }

    // (a) suppressed-by-prior-kept (4 k-groups)
    {
      int qo = tid & (CHUNK - 1);
      int ko = tid >> 7;
      if (qo < clen) {
        int q = c0 + qo;
        float qx1 = sx1[q], qy1 = sy1[q], qx2 = sx2[q], qy2 = sy2[q], qa = sar[q];
        int hit = 0;
        for (int k = ko; k < cnt; k += 4) {
          int kp = keptPos[k];
          float iw = fminf(sx2[kp], qx2) - fmaxf(sx1[kp], qx1);
          float ih = fminf(sy2[kp], qy2) - fmaxf(sy1[kp], qy1);
          iw = fmaxf(iw, 0.0f); ih = fmaxf(ih, 0.0f);
          float inter = iw * ih;
          float iou = inter / (sar[kp] + qa - inter);
          if (iou > iouT) hit = 1;
        }
        if (hit) suppPre[qo] = 1;
      }
    }

    // (b) intra-chunk pairwise (i<j): column-major suppression bits
    {
      int i = tid & (CHUNK - 1);
      if (i < clen) {
        int ip = c0 + i;
        float ix1 = sx1[ip], iy1 = sy1[ip], ix2 = sx2[ip], iy2 = sy2[ip], ia = sar[ip];
        for (int j = tid >> 7; j < clen; j += 4) {
          if (j <= i) continue;
          int q = c0 + j;
          float iw = fminf(ix2, sx2[q]) - fmaxf(ix1, sx1[q]);
          float ih = fminf(iy2, sy2[q]) - fmaxf(iy1, sy1[q]);
          iw = fmaxf(iw, 0.0f); ih = fmaxf(ih, 0.0f);
          float inter = iw * ih;
          float iou = inter / (ia + sar[q] - inter);
          if (iou > iouT) atomicOr(&colmask[j][i >> 5], 1u << (i & 31));
        }
      }
    }
    __syncthreads();

    // (c) single-wave ballot cascade (register-only serial walk)
    if (w == 0) {
      unsigned a0 = colmask[lane][0], a1 = colmask[lane][1];
      unsigned b0 = colmask[lane + 64][0], b1 = colmask[lane + 64][1];
      unsigned b2 = colmask[lane + 64][2], b3 = colmask[lane + 64][3];
      bool supA = (lane < clen) ? (suppPre[lane] != 0) : true;
      bool supB = (lane + 64 < clen) ? (suppPre[lane + 64] != 0) : true;
      bool doneA = (lane >= clen);
      bool doneB = (lane + 64 >= clen);
      int cl = cnt;
      while (cl < mOut) {                    // rows 0..63
        u64 cand = __ballot(!doneA && !supA);
        if (!cand) break;
        int r = __ffsll((long long)cand) - 1;
        if (lane == 0) keptPos[cl] = c0 + r;
        cl++;
        if (lane == r) doneA = true;
        unsigned av = (r < 32) ? a0 : a1;
        unsigned bv = (r < 32) ? b0 : b1;
        unsigned bit = (unsigned)r & 31;
        supA = supA || ((av >> bit) & 1);
        supB = supB || ((bv >> bit) & 1);
      }
      while (cl < mOut) {                    // rows 64..127
        u64 cand = __ballot(!doneB && !supB);
        if (!cand) break;
        int r = __ffsll((long long)cand) - 1;
        if (lane == 0) keptPos[cl] = c0 + 64 + r;
        cl++;
        if (lane == r) doneB = true;
        unsigned bv = (r < 32) ? b2 : b3;
        unsigned bit = (unsigned)r & 31;
        supB = supB || ((bv >> bit) & 1);
      }
      if (lane == 0) cntSh = cl;
    }
    __syncthreads();
    cnt = cntSh;
  }

  // emit [b, c, idx] rows, -1 padded
  int base = bc * slots * 3;
  for (int s = tid; s < slots; s += TB) {
    int v = (s < cnt) ? sidx[keptPos[s]] : -1;
    out[base + s * 3 + 0] = (v >= 0) ? b : -1;
    out[base + s * 3 + 1] = (v >= 0) ? c : -1;
    out[base + s * 3 + 2] = v;
  }
}

extern "C" void kernel_launch(void* const* d_in, const int* in_sizes, int n_in,
                              void* d_out, int out_size, void* d_ws, size_t ws_size,
                              hipStream_t stream) {
  const float* boxes  = (const float*)d_in[0];
  const float* scores = (const float*)d_in[1];
  const int*   maxOut = (const int*)d_in[2];
  const float* iouT   = (const float*)d_in[3];
  const float* scoreT = (const float*)d_in[4];
  int* out = (int*)d_out;
  u64* wsKeys = (u64*)d_ws;

  const int N = NBOX;
  int B = in_sizes[0] / (4 * N);
  int C = in_sizes[1] / (B * N);
  int slots = out_size / (B * C * 3);

  sort_half_kernel<<<dim3(B * C * 2), dim3(TA), 0, stream>>>(scores, wsKeys, C);
  nms_kernel<<<dim3(B * C), dim3(TB), 0, stream>>>(
      boxes, wsKeys, maxOut, iouT, scoreT, out, B, C, slots);
}